// Round 11
// baseline (826.887 us; speedup 1.0000x reference)
//
#include <hip/hip_runtime.h>
#include <hip/hip_bf16.h>
#include <cstdint>
#include <cstddef>

// ---------------------------------------------------------------------------
// SelfAttention (B=2, S=4096, H=2048, fp32 in/out), fp16 MFMA internally.
// Round 11: reads pipelined ONE PHASE AHEAD of their consuming MFMA (pure
// C++ ds_reads; compiler inserts counted lgkm waits). LDS pipe now runs
// under the MFMA pipe instead of alternating with it (the 42% plateau's
// mechanism). One barrier/phase; VMC(2)+SBAR only at ph4/ph8.
//   regs (fixed phase roles): afP=A0, afQ=A1, b0x=B0(buf0), b0y=B0(buf1),
//   b1=B1(shared). Phase p issues reads for phase p+1's MFMA.
//   stages: ph1 S1=b1.A0(t+1) ph2 S2=b1.A1(t+1) ph3 S3=b0.B0(t+2)
//           ph4 S4=b0.B1(t+2) ph5 S5=b0.A0(t+2) ph6 S6=b0.A1(t+2)
//           ph7 S7=b1.B0(t+3) ph8 S8=b1.B1(t+3)
//   ph4 fence: outstanding {S7',S8',S1,S2,S3}=10, VMC(2) drains t+1 set.
//   ph8 fence: outstanding {S3..S7}=10, VMC(2) drains t+2 set.
//   WAR: every region's last read drains >=2 barriers before its re-stage.
// fp16 scores (round 10, verified) retained.
// ---------------------------------------------------------------------------

typedef _Float16 half8 __attribute__((ext_vector_type(8)));
typedef _Float16 half4 __attribute__((ext_vector_type(4)));
typedef float    f32x4 __attribute__((ext_vector_type(4)));

__device__ __forceinline__ void gld_lds16(const void* g, void* l) {
  __builtin_amdgcn_global_load_lds(
      (const __attribute__((address_space(1))) unsigned int*)g,
      (__attribute__((address_space(3))) unsigned int*)l, 16, 0, 0);
}

#define FENCE()  asm volatile("" ::: "memory")
#define VMC(n)   asm volatile("s_waitcnt vmcnt(" #n ")" ::: "memory")
#define SBAR()   do { __builtin_amdgcn_s_barrier(); FENCE(); } while (0)
#define SCHED0() __builtin_amdgcn_sched_barrier(0)
#define PRIO1()  __builtin_amdgcn_s_setprio(1)
#define PRIO0()  __builtin_amdgcn_s_setprio(0)

// A subtile (m-half MH) from buffer RB: 8 x ds_read_b128 (C++ reads)
#define LOAD_A(dst, RB, MH) do {                                            \
  const char* _p = ldsA + ((RB)*2 + wr) * 16384 + fr * 128;                 \
  _Pragma("unroll") for (int mi = 0; mi < 4; ++mi) {                        \
    dst[mi][0] = *(const half8*)(_p + ((MH)*4 + mi) * 2048 + cS0);          \
    dst[mi][1] = *(const half8*)(_p + ((MH)*4 + mi) * 2048 + cS1);          \
  }                                                                         \
} while (0)

// B subtile (n-half NH) from buffer RB: 4 x ds_read_b128
#define LOAD_B(dst, RB, NH) do {                                            \
  const char* _p = ldsB + ((RB)*2 + (wc >> 1)) * 16384 +                    \
                   ((wc & 1) * 64 + fr) * 128;                              \
  _Pragma("unroll") for (int ni = 0; ni < 2; ++ni) {                        \
    dst[ni][0] = *(const half8*)(_p + ((NH)*2 + ni) * 2048 + cS0);          \
    dst[ni][1] = *(const half8*)(_p + ((NH)*2 + ni) * 2048 + cS1);          \
  }                                                                         \
} while (0)

// one C-quadrant x K=64: 16 MFMA
#define MFMA_Q(AF, BF, MH, NH)                                              \
  PRIO1();                                                                  \
  _Pragma("unroll") for (int mi = 0; mi < 4; ++mi)                          \
  _Pragma("unroll") for (int ni = 0; ni < 2; ++ni) {                        \
    f32x4& _c = acc[(MH)*4 + mi][(NH)*2 + ni];                              \
    _c = __builtin_amdgcn_mfma_f32_16x16x32_f16(AF[mi][0], BF[ni][0], _c, 0, 0, 0); \
    _c = __builtin_amdgcn_mfma_f32_16x16x32_f16(AF[mi][1], BF[ni][1], _c, 0, 0, 0); \
  }                                                                         \
  PRIO0();

// stage one 128x64 half-tile (16KB): 2 x global_load_lds(16B) per wave.
#define STAGE_A(bsel, h, kof)                                               \
  {                                                                         \
    const _Float16* _s = Abase + (size_t)((h) * 128) * lda + (kof);         \
    char* _d = ldsA + ((bsel)*2 + (h)) * 16384 + wvd;                       \
    gld_lds16(_s, _d);                                                      \
    gld_lds16(_s + lda8, _d + 1024);                                        \
  }
#define STAGE_B(bsel, h, kof)                                               \
  {                                                                         \
    const _Float16* _s = Bbase + (size_t)((h) * 128) * ldb + (kof);         \
    char* _d = ldsB + ((bsel)*2 + (h)) * 16384 + wvd;                       \
    gld_lds16(_s, _d);                                                      \
    gld_lds16(_s + ldb8, _d + 1024);                                        \
  }

// MODE 0: fp32 row-major, no bias      (final out)
// MODE 1: fp16 row-major + bias        (Q, K projections)
// MODE 2: fp16 TRANSPOSED + bias       (V -> Vt[col*ldo + row])
// MODE 3: fp16 row-major, no bias      (scores S)
template <int MODE>
__global__ __launch_bounds__(512) void gemm256(
    const _Float16* __restrict__ A, int lda,
    const _Float16* __restrict__ B, int ldb,
    const float* __restrict__ bias,
    void* __restrict__ out, int ldo, int K,
    size_t sA, size_t sB, size_t sO)
{
  __shared__ __attribute__((aligned(128))) char lds[131072];
  char* ldsA = (char*)lds;       // region: (bsel*2+half)*16384
  char* ldsB = (char*)lds + 65536;

  const int tid  = threadIdx.x;
  const int wv   = tid >> 6;
  const int lane = tid & 63;
  const int wr = wv >> 2;           // wave row (M half, 128 rows)
  const int wc = wv & 3;            // wave col (64 cols)
  const int bm = blockIdx.x * 256;
  const int bn = blockIdx.y * 256;
  A += (size_t)blockIdx.z * sA;
  B += (size_t)blockIdx.z * sB;

  // fragment-read indexing (swizzle verified rounds 2-10)
  const int fr = lane & 15;
  const int kq = lane >> 4;
  const int sx = (fr & 7) << 4;
  const int cS0 = (kq * 16) ^ sx;
  const int cS1 = (64 + kq * 16) ^ sx;
  // staging indexing (verified rounds 2-10)
  const int lr  = lane >> 3;
  const int sc8 = ((lane & 7) ^ (lr & 7)) << 3;

  const _Float16* Abase = A + (size_t)(bm + wv * 16 + lr) * lda + sc8;
  const _Float16* Bbase = B + (size_t)(bn + wv * 16 + lr) * ldb + sc8;
  const size_t lda8 = (size_t)lda * 8, ldb8 = (size_t)ldb * 8;
  const int wvd = wv * 2048;

  f32x4 acc[8][4];
  const f32x4 zf = {0.f, 0.f, 0.f, 0.f};
#pragma unroll
  for (int mi = 0; mi < 8; ++mi)
#pragma unroll
    for (int ni = 0; ni < 4; ++ni) acc[mi][ni] = zf;

  // fixed-role register sets (compile-time indices everywhere)
  half8 afP[4][2], afQ[4][2];       // A0 / A1 subtiles
  half8 b0x[2][2], b0y[2][2];       // B0 of buf0 / buf1
  half8 b1[2][2];                   // B1 (shared, short-lived)

  const int NT = K >> 6;        // 32 or 64 (even, >= 2)
  const int NI = NT >> 1;

  // prologue: t0 full (8 ops) + t1.{B0,B1} (4 ops); VMC(4) drains t0.
  STAGE_A(0, 0, 0); STAGE_A(0, 1, 0); STAGE_B(0, 0, 0); STAGE_B(0, 1, 0);
  STAGE_B(1, 0, 64); STAGE_B(1, 1, 64);
  VMC(4);
  SBAR();
  LOAD_A(afP, 0, 0);            // buf0.A0(t0) -> ph1,ph2
  LOAD_B(b0x, 0, 0);            // buf0.B0(t0) -> ph1,ph4
  SCHED0();

  for (int it = 0; it < NI; ++it) {
    const bool more = (it < NI - 1);
    const size_t t1k = (size_t)(2 * it + 1) * 64;
    const size_t t2k = t1k + 64;
    const size_t t3k = t1k + 128;

    // ph1 (buf0, Q00) — reads b1 for ph2; stage S1
    SBAR();
    LOAD_B(b1, 0, 1);
    STAGE_A(1, 0, t1k);
    SCHED0();
    MFMA_Q(afP, b0x, 0, 0);
    // ph2 (Q01) — reads afQ for ph3; stage S2
    SBAR();
    LOAD_A(afQ, 0, 1);
    STAGE_A(1, 1, t1k);
    SCHED0();
    MFMA_Q(afP, b1, 0, 1);
    // ph3 (Q11) — stage S3
    SBAR();
    if (more) STAGE_B(0, 0, t2k);
    SCHED0();
    MFMA_Q(afQ, b1, 1, 1);
    // ph4 (Q10) — fence t+1; reads afP,b0y (t+1) for ph5; stage S4
    if (more) { VMC(2); } else { VMC(0); }
    SBAR();
    LOAD_A(afP, 1, 0);
    LOAD_B(b0y, 1, 0);
    if (more) STAGE_B(0, 1, t2k);
    SCHED0();
    MFMA_Q(afQ, b0x, 1, 0);
    // ph5 (buf1, Q00) — reads b1 for ph6; stage S5
    SBAR();
    LOAD_B(b1, 1, 1);
    if (more) STAGE_A(0, 0, t2k);
    SCHED0();
    MFMA_Q(afP, b0y, 0, 0);
    // ph6 (Q01) — reads afQ for ph7; stage S6
    SBAR();
    LOAD_A(afQ, 1, 1);
    if (more) STAGE_A(0, 1, t2k);
    SCHED0();
    MFMA_Q(afP, b1, 0, 1);
    // ph7 (Q11) — stage S7
    SBAR();
    if (more) STAGE_B(1, 0, t3k);
    SCHED0();
    MFMA_Q(afQ, b1, 1, 1);
    // ph8 (Q10) — fence t+2; reads afP,b0x (t+2) for next ph1; stage S8
    if (more) {
      VMC(2);
      SBAR();
      LOAD_A(afP, 0, 0);
      LOAD_B(b0x, 0, 0);
      STAGE_B(1, 1, t3k);
      SCHED0();
    } else {
      SBAR();
    }
    MFMA_Q(afQ, b0y, 1, 0);
  }

  // epilogue. C/D frag: col = lane&15, rows = (lane>>4)*4 + j
#pragma unroll
  for (int mi = 0; mi < 8; ++mi) {
#pragma unroll
    for (int ni = 0; ni < 4; ++ni) {
      const int col  = bn + wc * 64 + ni * 16 + fr;
      const int row0 = bm + wr * 128 + mi * 16 + kq * 4;
      const f32x4 a = acc[mi][ni];
      if constexpr (MODE == 0) {
        float* O = (float*)out + (size_t)blockIdx.z * sO;
#pragma unroll
        for (int j = 0; j < 4; ++j) O[(size_t)(row0 + j) * ldo + col] = a[j];
      } else if constexpr (MODE == 1) {
        _Float16* O = (_Float16*)out;
        const float bb = bias[col];
#pragma unroll
        for (int j = 0; j < 4; ++j)
          O[(size_t)(row0 + j) * ldo + col] = (_Float16)(a[j] + bb);
      } else if constexpr (MODE == 2) {
        _Float16* O = (_Float16*)out;
        const float bb = bias[col];
        half4 h;
#pragma unroll
        for (int j = 0; j < 4; ++j) h[j] = (_Float16)(a[j] + bb);
        *(half4*)(O + (size_t)col * ldo + row0) = h;
      } else {  // MODE 3: fp16 row-major, no bias (scores)
        _Float16* O = (_Float16*)out + (size_t)blockIdx.z * sO;
#pragma unroll
        for (int j = 0; j < 4; ++j)
          O[(size_t)(row0 + j) * ldo + col] = (_Float16)a[j];
      }
    }
  }
}

__device__ __forceinline__ float wave_max_f(float v) {
#pragma unroll
  for (int o = 32; o; o >>= 1) v = fmaxf(v, __shfl_xor(v, o));
  return v;
}
__device__ __forceinline__ float wave_sum_f(float v) {
#pragma unroll
  for (int o = 32; o; o >>= 1) v += __shfl_xor(v, o);
  return v;
}

// one 256-thread block per row of 4096 fp16 scores -> fp16 probabilities
__global__ __launch_bounds__(256) void softmax_rows(
    const _Float16* __restrict__ S, _Float16* __restrict__ P)
{
  __shared__ float rmax[4], rsum[4];
  const int tid = threadIdx.x;
  const _Float16* s = S + (size_t)blockIdx.x * 4096;
  _Float16*       p = P + (size_t)blockIdx.x * 4096;

  const half8 v0 = ((const half8*)s)[tid];
  const half8 v1 = ((const half8*)s)[tid + 256];
  float f[16];
#pragma unroll
  for (int j = 0; j < 8; ++j) { f[j] = (float)v0[j]; f[8 + j] = (float)v1[j]; }

  float m = f[0];
#pragma unroll
  for (int j = 1; j < 16; ++j) m = fmaxf(m, f[j]);
  m = wave_max_f(m);
  if ((tid & 63) == 0) rmax[tid >> 6] = m;
  __syncthreads();
  m = fmaxf(fmaxf(rmax[0], rmax[1]), fmaxf(rmax[2], rmax[3]));

  float sum = 0.f;
#pragma unroll
  for (int j = 0; j < 16; ++j) { f[j] = __expf(f[j] - m); sum += f[j]; }
  sum = wave_sum_f(sum);
  if ((tid & 63) == 0) rsum[tid >> 6] = sum;
  __syncthreads();
  sum = rsum[0] + rsum[1] + rsum[2] + rsum[3];
  const float inv = 1.0f / sum;

  half8 o0, o1;
#pragma unroll
  for (int j = 0; j < 8; ++j) {
    o0[j] = (_Float16)(f[j] * inv);
    o1[j] = (_Float16)(f[8 + j] * inv);
  }
  ((half8*)p)[tid] = o0;
  ((half8*)p)[tid + 256] = o1;
}

__global__ __launch_bounds__(256) void cvt_f32_f16(
    const float* __restrict__ in, _Float16* __restrict__ out, int n4)
{
  const int stride = gridDim.x * 256;
  for (int idx = blockIdx.x * 256 + threadIdx.x; idx < n4; idx += stride) {
    const f32x4 x = ((const f32x4*)in)[idx];
    half4 h;
#pragma unroll
    for (int j = 0; j < 4; ++j) h[j] = (_Float16)x[j];
    ((half4*)out)[idx] = h;
  }
}

extern "C" void kernel_launch(void* const* d_in, const int* in_sizes, int n_in,
                              void* d_out, int out_size, void* d_ws, size_t ws_size,
                              hipStream_t stream)
{
  const float* X  = (const float*)d_in[0];
  const float* Wq = (const float*)d_in[1];
  const float* bq = (const float*)d_in[2];
  const float* Wk = (const float*)d_in[3];
  const float* bk = (const float*)d_in[4];
  const float* Wv = (const float*)d_in[5];
  const float* bv = (const float*)d_in[6];
  float* out = (float*)d_out;

  const size_t NX = (size_t)2 * 4096 * 2048;  // 16,777,216
  const size_t NW = (size_t)2048 * 2048;      //  4,194,304
  const size_t NS = (size_t)2 * 4096 * 4096;  // 33,554,432

  // Workspace layout (lifetime-aliased):
  //  [0 ..)         : Ssc fp16 (67MB) — earlier hosts Xh + W*h fp16
  //  [NS*4 ..)      : Q | Kp fp16 — later aliased by P fp16
  //  [NS*4+2*NX*2..): Vt fp16 [2048][8192]
  char* w = (char*)d_ws;
  _Float16* Ssc = (_Float16*)w;
  _Float16* Xh  = (_Float16*)w;
  _Float16* Wqh = (_Float16*)(w + NX * 2);
  _Float16* Wkh = (_Float16*)(w + NX * 2 + NW * 2);
  _Float16* Wvh = (_Float16*)(w + NX * 2 + 2 * NW * 2);
  _Float16* Q   = (_Float16*)(w + NS * 4);
  _Float16* Kp  = (_Float16*)(w + NS * 4 + NX * 2);
  _Float16* P   = (_Float16*)(w + NS * 4);            // aliases Q+Kp
  _Float16* Vt  = (_Float16*)(w + NS * 4 + 2 * NX * 2);

  // 1) fp32 -> fp16 conversions
  cvt_f32_f16<<<2048, 256, 0, stream>>>(X,  Xh,  (int)(NX / 4));
  cvt_f32_f16<<<512,  256, 0, stream>>>(Wq, Wqh, (int)(NW / 4));
  cvt_f32_f16<<<512,  256, 0, stream>>>(Wk, Wkh, (int)(NW / 4));
  cvt_f32_f16<<<512,  256, 0, stream>>>(Wv, Wvh, (int)(NW / 4));

  const dim3 blk(512);
  // 2) projections: [8192,2048] = Xh @ W^T + b
  gemm256<1><<<dim3(32, 8, 1), blk, 0, stream>>>(Xh, 2048, Wqh, 2048, bq,
                                                 Q, 2048, 2048, 0, 0, 0);
  gemm256<1><<<dim3(32, 8, 1), blk, 0, stream>>>(Xh, 2048, Wkh, 2048, bk,
                                                 Kp, 2048, 2048, 0, 0, 0);
  gemm256<2><<<dim3(32, 8, 1), blk, 0, stream>>>(Xh, 2048, Wvh, 2048, bv,
                                                 Vt, 8192, 2048, 0, 0, 0);
  // 3) scores: per batch, S = Q K^T (fp16 out)
  gemm256<3><<<dim3(16, 16, 2), blk, 0, stream>>>(
      Q, 2048, Kp, 2048, nullptr, Ssc, 4096, 2048,
      (size_t)4096 * 2048, (size_t)4096 * 2048, (size_t)4096 * 4096);
  // 4) row softmax (fp16 in) -> fp16 probs
  softmax_rows<<<8192, 256, 0, stream>>>(Ssc, P);
  // 5) out: per batch, [4096,2048] = P @ Vt^T
  gemm256<0><<<dim3(16, 8, 2), blk, 0, stream>>>(
      P, 4096, Vt, 8192, nullptr, out, 2048, 4096,
      (size_t)4096 * 4096, (size_t)4096, (size_t)4096 * 2048);
}

// Round 12
// 501.103 us; speedup vs baseline: 1.6501x; 1.6501x over previous
//
#include <hip/hip_runtime.h>
#include <hip/hip_bf16.h>
#include <cstdint>
#include <cstddef>

// ---------------------------------------------------------------------------
// SelfAttention (B=2, S=4096, H=2048, fp32 in/out), fp16 MFMA internally.
// Round 12: round-10 GEMM skeleton byte-identical (verified stable, 489us).
// Single change: gemm256 is ONE instantiation with runtime `mode` (was 4
// co-compiled template instantiations — rule #19: co-compiled variants
// perturb each other's regalloc by up to ~8%; K-loop codegen now unique).
// MODE 0: fp32 row-major out | 1: fp16 +bias | 2: fp16 transposed +bias |
// 3: fp16 row-major (scores). fp16 scores retained (round 10, verified).
// ---------------------------------------------------------------------------

typedef _Float16 half8 __attribute__((ext_vector_type(8)));
typedef _Float16 half4 __attribute__((ext_vector_type(4)));
typedef float    f32x4 __attribute__((ext_vector_type(4)));

__device__ __forceinline__ void gld_lds16(const void* g, void* l) {
  __builtin_amdgcn_global_load_lds(
      (const __attribute__((address_space(1))) unsigned int*)g,
      (__attribute__((address_space(3))) unsigned int*)l, 16, 0, 0);
}

#define FENCE()  asm volatile("" ::: "memory")
#define LGKM(n)  asm volatile("s_waitcnt lgkmcnt(" #n ")" ::: "memory")
#define VMC(n)   asm volatile("s_waitcnt vmcnt(" #n ")" ::: "memory")
#define SBAR()   do { __builtin_amdgcn_s_barrier(); FENCE(); } while (0)
#define SCHED0() __builtin_amdgcn_sched_barrier(0)
#define PRIO1()  __builtin_amdgcn_s_setprio(1)
#define PRIO0()  __builtin_amdgcn_s_setprio(0)

// A subtile (m-half MH) from buffer RB into af: 8 x ds_read_b128 (C++ reads)
#define LOAD_A(dst, RB, MH) do {                                            \
  const char* _p = ldsA + ((RB)*2 + wr) * 16384 + fr * 128;                 \
  _Pragma("unroll") for (int mi = 0; mi < 4; ++mi) {                        \
    dst[mi][0] = *(const half8*)(_p + ((MH)*4 + mi) * 2048 + cS0);          \
    dst[mi][1] = *(const half8*)(_p + ((MH)*4 + mi) * 2048 + cS1);          \
  }                                                                         \
} while (0)

// B subtile (n-half NH) from buffer RB into dst: 4 x ds_read_b128
#define LOAD_B(dst, RB, NH) do {                                            \
  const char* _p = ldsB + ((RB)*2 + (wc >> 1)) * 16384 +                    \
                   ((wc & 1) * 64 + fr) * 128;                              \
  _Pragma("unroll") for (int ni = 0; ni < 2; ++ni) {                        \
    dst[ni][0] = *(const half8*)(_p + ((NH)*2 + ni) * 2048 + cS0);          \
    dst[ni][1] = *(const half8*)(_p + ((NH)*2 + ni) * 2048 + cS1);          \
  }                                                                         \
} while (0)

// one C-quadrant x K=64: 16 MFMA
#define MFMA_Q(AF, BF, MH, NH)                                              \
  _Pragma("unroll") for (int mi = 0; mi < 4; ++mi)                          \
  _Pragma("unroll") for (int ni = 0; ni < 2; ++ni) {                        \
    f32x4& _c = acc[(MH)*4 + mi][(NH)*2 + ni];                              \
    _c = __builtin_amdgcn_mfma_f32_16x16x32_f16(AF[mi][0], BF[ni][0], _c, 0, 0, 0); \
    _c = __builtin_amdgcn_mfma_f32_16x16x32_f16(AF[mi][1], BF[ni][1], _c, 0, 0, 0); \
  }

// stage one 128x64 half-tile (16KB): 2 x global_load_lds(16B) per wave.
// LDS linear; global source column pre-swizzled (involution, both-sides).
#define STAGE_A(bsel, h, kof)                                               \
  {                                                                         \
    const _Float16* _s = Abase + (size_t)((h) * 128) * lda + (kof);         \
    char* _d = ldsA + ((bsel)*2 + (h)) * 16384 + wvd;                       \
    gld_lds16(_s, _d);                                                      \
    gld_lds16(_s + lda8, _d + 1024);                                        \
  }
#define STAGE_B(bsel, h, kof)                                               \
  {                                                                         \
    const _Float16* _s = Bbase + (size_t)((h) * 128) * ldb + (kof);         \
    char* _d = ldsB + ((bsel)*2 + (h)) * 16384 + wvd;                       \
    gld_lds16(_s, _d);                                                      \
    gld_lds16(_s + ldb8, _d + 1024);                                        \
  }

__global__ __launch_bounds__(512) void gemm256(
    const _Float16* __restrict__ A, int lda,
    const _Float16* __restrict__ B, int ldb,
    const float* __restrict__ bias,
    void* __restrict__ out, int ldo, int K,
    size_t sA, size_t sB, size_t sO, int mode)
{
  __shared__ __attribute__((aligned(128))) char lds[131072];
  char* ldsA = (char*)lds;       // region: (bsel*2+half)*16384
  char* ldsB = (char*)lds + 65536;

  const int tid  = threadIdx.x;
  const int wv   = tid >> 6;
  const int lane = tid & 63;
  const int wr = wv >> 2;           // wave row (M half, 128 rows)
  const int wc = wv & 3;            // wave col (64 cols)
  const int bm = blockIdx.x * 256;
  const int bn = blockIdx.y * 256;
  A += (size_t)blockIdx.z * sA;
  B += (size_t)blockIdx.z * sB;

  // fragment-read indexing (swizzle verified rounds 2-10)
  const int fr = lane & 15;
  const int kq = lane >> 4;
  const int sx = (fr & 7) << 4;
  const int cS0 = (kq * 16) ^ sx;
  const int cS1 = (64 + kq * 16) ^ sx;
  // staging indexing (verified rounds 2-10)
  const int lr  = lane >> 3;
  const int sc8 = ((lane & 7) ^ (lr & 7)) << 3;

  const _Float16* Abase = A + (size_t)(bm + wv * 16 + lr) * lda + sc8;
  const _Float16* Bbase = B + (size_t)(bn + wv * 16 + lr) * ldb + sc8;
  const size_t lda8 = (size_t)lda * 8, ldb8 = (size_t)ldb * 8;
  const int wvd = wv * 2048;

  f32x4 acc[8][4];
  const f32x4 zf = {0.f, 0.f, 0.f, 0.f};
#pragma unroll
  for (int mi = 0; mi < 8; ++mi)
#pragma unroll
    for (int ni = 0; ni < 4; ++ni) acc[mi][ni] = zf;

  half8 af[4][2], bf0[2][2], bf1[2][2];

  const int NT = K >> 6;        // 32 or 64 (even, >= 4)
  const int NI = NT >> 1;

  // prologue: t0 full (8 loads) + t1.{B0,B1} (4 loads); VMC(4) drains t0.
  STAGE_A(0, 0, 0); STAGE_A(0, 1, 0); STAGE_B(0, 0, 0); STAGE_B(0, 1, 0);
  STAGE_B(1, 0, 64); STAGE_B(1, 1, 64);
  VMC(4);
  SBAR();

  for (int it = 0; it < NI; ++it) {
    const bool more = (it < NI - 1);
    const size_t t1k = (size_t)(2 * it + 1) * 64;   // buf1 tile (this group)
    const size_t t2k = t1k + 64;                    // buf0 next tile
    const size_t t3k = t1k + 128;                   // buf1 next tile

    // ===== group 1: buf0, tile 2it =====
    // ph1: reads A(MH0)+B(NH0) (12); stage buf1.A0(t+1)
    LOAD_A(af, 0, 0); LOAD_B(bf0, 0, 0);
    STAGE_A(1, 0, t1k);
    LGKM(8);
    SBAR(); LGKM(0); SCHED0();
    PRIO1(); MFMA_Q(af, bf0, 0, 0); PRIO0();
    SBAR();
    // ph2: reads B(NH1) (4); stage buf1.A1(t+1)
    LOAD_B(bf1, 0, 1);
    STAGE_A(1, 1, t1k);
    SBAR(); LGKM(0); SCHED0();
    PRIO1(); MFMA_Q(af, bf1, 0, 1); PRIO0();
    SBAR();
    // ph3: reads A(MH1) (8); stage buf0.B0(t+2)
    LOAD_A(af, 0, 1);
    if (more) STAGE_B(0, 0, t2k);
    SBAR(); LGKM(0); SCHED0();
    PRIO1(); MFMA_Q(af, bf1, 1, 1); PRIO0();
    SBAR();
    // ph4: no reads; stage buf0.B1(t+2); VMC drains ALL t+1 stages
    if (more) STAGE_B(0, 1, t2k);
    SBAR(); SCHED0();
    PRIO1(); MFMA_Q(af, bf0, 1, 0); PRIO0();
    if (more) { VMC(4); } else { VMC(0); }
    SBAR();

    // ===== group 2: buf1, tile 2it+1 =====
    // ph5: reads A(MH0)+B(NH0) (12); stage buf0.A0(t+2)
    LOAD_A(af, 1, 0); LOAD_B(bf0, 1, 0);
    if (more) STAGE_A(0, 0, t2k);
    LGKM(8);
    SBAR(); LGKM(0); SCHED0();
    PRIO1(); MFMA_Q(af, bf0, 0, 0); PRIO0();
    SBAR();
    // ph6: reads B(NH1) (4); stage buf0.A1(t+2)
    LOAD_B(bf1, 1, 1);
    if (more) STAGE_A(0, 1, t2k);
    SBAR(); LGKM(0); SCHED0();
    PRIO1(); MFMA_Q(af, bf1, 0, 1); PRIO0();
    SBAR();
    // ph7: reads A(MH1) (8); stage buf1.B0(t+3)
    LOAD_A(af, 1, 1);
    if (more) STAGE_B(1, 0, t3k);
    SBAR(); LGKM(0); SCHED0();
    PRIO1(); MFMA_Q(af, bf1, 1, 1); PRIO0();
    SBAR();
    // ph8: no reads; stage buf1.B1(t+3); VMC drains ALL t+2 stages
    if (more) STAGE_B(1, 1, t3k);
    SBAR(); SCHED0();
    PRIO1(); MFMA_Q(af, bf0, 1, 0); PRIO0();
    if (more) { VMC(4); } else { VMC(0); }
    SBAR();
  }

  // epilogue (runtime mode; executes once). C/D: col=lane&15, rows=kq*4+j
#pragma unroll
  for (int mi = 0; mi < 8; ++mi) {
#pragma unroll
    for (int ni = 0; ni < 4; ++ni) {
      const int col  = bn + wc * 64 + ni * 16 + fr;
      const int row0 = bm + wr * 128 + mi * 16 + kq * 4;
      const f32x4 a = acc[mi][ni];
      if (mode == 0) {
        float* O = (float*)out + (size_t)blockIdx.z * sO;
#pragma unroll
        for (int j = 0; j < 4; ++j) O[(size_t)(row0 + j) * ldo + col] = a[j];
      } else if (mode == 1) {
        _Float16* O = (_Float16*)out;
        const float bb = bias[col];
#pragma unroll
        for (int j = 0; j < 4; ++j)
          O[(size_t)(row0 + j) * ldo + col] = (_Float16)(a[j] + bb);
      } else if (mode == 2) {
        _Float16* O = (_Float16*)out;
        const float bb = bias[col];
        half4 h;
#pragma unroll
        for (int j = 0; j < 4; ++j) h[j] = (_Float16)(a[j] + bb);
        *(half4*)(O + (size_t)col * ldo + row0) = h;
      } else {  // mode 3: fp16 row-major, no bias (scores)
        _Float16* O = (_Float16*)out + (size_t)blockIdx.z * sO;
#pragma unroll
        for (int j = 0; j < 4; ++j)
          O[(size_t)(row0 + j) * ldo + col] = (_Float16)a[j];
      }
    }
  }
}

__device__ __forceinline__ float wave_max_f(float v) {
#pragma unroll
  for (int o = 32; o; o >>= 1) v = fmaxf(v, __shfl_xor(v, o));
  return v;
}
__device__ __forceinline__ float wave_sum_f(float v) {
#pragma unroll
  for (int o = 32; o; o >>= 1) v += __shfl_xor(v, o);
  return v;
}

// one 256-thread block per row of 4096 fp16 scores -> fp16 probabilities
__global__ __launch_bounds__(256) void softmax_rows(
    const _Float16* __restrict__ S, _Float16* __restrict__ P)
{
  __shared__ float rmax[4], rsum[4];
  const int tid = threadIdx.x;
  const _Float16* s = S + (size_t)blockIdx.x * 4096;
  _Float16*       p = P + (size_t)blockIdx.x * 4096;

  const half8 v0 = ((const half8*)s)[tid];
  const half8 v1 = ((const half8*)s)[tid + 256];
  float f[16];
#pragma unroll
  for (int j = 0; j < 8; ++j) { f[j] = (float)v0[j]; f[8 + j] = (float)v1[j]; }

  float m = f[0];
#pragma unroll
  for (int j = 1; j < 16; ++j) m = fmaxf(m, f[j]);
  m = wave_max_f(m);
  if ((tid & 63) == 0) rmax[tid >> 6] = m;
  __syncthreads();
  m = fmaxf(fmaxf(rmax[0], rmax[1]), fmaxf(rmax[2], rmax[3]));

  float sum = 0.f;
#pragma unroll
  for (int j = 0; j < 16; ++j) { f[j] = __expf(f[j] - m); sum += f[j]; }
  sum = wave_sum_f(sum);
  if ((tid & 63) == 0) rsum[tid >> 6] = sum;
  __syncthreads();
  sum = rsum[0] + rsum[1] + rsum[2] + rsum[3];
  const float inv = 1.0f / sum;

  half8 o0, o1;
#pragma unroll
  for (int j = 0; j < 8; ++j) {
    o0[j] = (_Float16)(f[j] * inv);
    o1[j] = (_Float16)(f[8 + j] * inv);
  }
  ((half8*)p)[tid] = o0;
  ((half8*)p)[tid + 256] = o1;
}

__global__ __launch_bounds__(256) void cvt_f32_f16(
    const float* __restrict__ in, _Float16* __restrict__ out, int n4)
{
  const int stride = gridDim.x * 256;
  for (int idx = blockIdx.x * 256 + threadIdx.x; idx < n4; idx += stride) {
    const f32x4 x = ((const f32x4*)in)[idx];
    half4 h;
#pragma unroll
    for (int j = 0; j < 4; ++j) h[j] = (_Float16)x[j];
    ((half4*)out)[idx] = h;
  }
}

extern "C" void kernel_launch(void* const* d_in, const int* in_sizes, int n_in,
                              void* d_out, int out_size, void* d_ws, size_t ws_size,
                              hipStream_t stream)
{
  const float* X  = (const float*)d_in[0];
  const float* Wq = (const float*)d_in[1];
  const float* bq = (const float*)d_in[2];
  const float* Wk = (const float*)d_in[3];
  const float* bk = (const float*)d_in[4];
  const float* Wv = (const float*)d_in[5];
  const float* bv = (const float*)d_in[6];
  float* out = (float*)d_out;

  const size_t NX = (size_t)2 * 4096 * 2048;  // 16,777,216
  const size_t NW = (size_t)2048 * 2048;      //  4,194,304
  const size_t NS = (size_t)2 * 4096 * 4096;  // 33,554,432

  // Workspace layout (lifetime-aliased):
  //  [0 ..)         : Ssc fp16 (67MB) — earlier hosts Xh + W*h fp16
  //  [NS*4 ..)      : Q | Kp fp16 — later aliased by P fp16
  //  [NS*4+2*NX*2..): Vt fp16 [2048][8192]
  char* w = (char*)d_ws;
  _Float16* Ssc = (_Float16*)w;
  _Float16* Xh  = (_Float16*)w;
  _Float16* Wqh = (_Float16*)(w + NX * 2);
  _Float16* Wkh = (_Float16*)(w + NX * 2 + NW * 2);
  _Float16* Wvh = (_Float16*)(w + NX * 2 + 2 * NW * 2);
  _Float16* Q   = (_Float16*)(w + NS * 4);
  _Float16* Kp  = (_Float16*)(w + NS * 4 + NX * 2);
  _Float16* P   = (_Float16*)(w + NS * 4);            // aliases Q+Kp
  _Float16* Vt  = (_Float16*)(w + NS * 4 + 2 * NX * 2);

  // 1) fp32 -> fp16 conversions
  cvt_f32_f16<<<2048, 256, 0, stream>>>(X,  Xh,  (int)(NX / 4));
  cvt_f32_f16<<<512,  256, 0, stream>>>(Wq, Wqh, (int)(NW / 4));
  cvt_f32_f16<<<512,  256, 0, stream>>>(Wk, Wkh, (int)(NW / 4));
  cvt_f32_f16<<<512,  256, 0, stream>>>(Wv, Wvh, (int)(NW / 4));

  const dim3 blk(512);
  // 2) projections: [8192,2048] = Xh @ W^T + b
  gemm256<<<dim3(32, 8, 1), blk, 0, stream>>>(Xh, 2048, Wqh, 2048, bq,
                                              Q, 2048, 2048, 0, 0, 0, 1);
  gemm256<<<dim3(32, 8, 1), blk, 0, stream>>>(Xh, 2048, Wkh, 2048, bk,
                                              Kp, 2048, 2048, 0, 0, 0, 1);
  gemm256<<<dim3(32, 8, 1), blk, 0, stream>>>(Xh, 2048, Wvh, 2048, bv,
                                              Vt, 8192, 2048, 0, 0, 0, 2);
  // 3) scores: per batch, S = Q K^T (fp16 out)
  gemm256<<<dim3(16, 16, 2), blk, 0, stream>>>(
      Q, 2048, Kp, 2048, nullptr, Ssc, 4096, 2048,
      (size_t)4096 * 2048, (size_t)4096 * 2048, (size_t)4096 * 4096, 3);
  // 4) row softmax (fp16 in) -> fp16 probs
  softmax_rows<<<8192, 256, 0, stream>>>(Ssc, P);
  // 5) out: per batch, [4096,2048] = P @ Vt^T
  gemm256<<<dim3(16, 8, 2), blk, 0, stream>>>(
      P, 4096, Vt, 8192, nullptr, out, 2048, 4096,
      (size_t)4096 * 4096, (size_t)4096, (size_t)4096 * 2048, 0);
}